// Round 1
// baseline (428.979 us; speedup 1.0000x reference)
//
#include <hip/hip_runtime.h>

typedef unsigned short u16;
typedef __bf16 bf16x8 __attribute__((ext_vector_type(8)));
typedef float f32x4 __attribute__((ext_vector_type(4)));

constexpr int B_ = 2, T_ = 2048, D_ = 2048, H_ = 16, HD_ = 128;
constexpr int MROWS = B_ * T_;   // 4096
constexpr int KD = D_;
constexpr int ND = D_;
// softmax in exp2 domain: logits pre-scaled by 1/sqrt(128) * log2(e)
#define SL2E (0.08838834764831845f * 1.4426950408889634f)

__device__ __forceinline__ u16 f2bf(float f) {
  unsigned u = __float_as_uint(f);
  u += 0x7FFF + ((u >> 16) & 1);   // RNE; inputs never NaN
  return (u16)(u >> 16);
}

__device__ __forceinline__ float fexp2(float x) { return __builtin_amdgcn_exp2f(x); }

// async global->LDS, 16B per lane; dest = wave-uniform base + lane*16
__device__ __forceinline__ void async16(const void* g, void* l) {
  __builtin_amdgcn_global_load_lds((__attribute__((address_space(1))) void*)g,
                                   (__attribute__((address_space(3))) void*)l,
                                   16, 0, 0);
}

#define MEMFENCE asm volatile("" ::: "memory")

__global__ void cvt_kernel(const float* __restrict__ in, u16* __restrict__ out, int n) {
  int i = (blockIdx.x * blockDim.x + threadIdx.x) * 4;
  if (i >= n) return;
  const float4 v = *(const float4*)(in + i);
  ushort4 h;
  h.x = f2bf(v.x); h.y = f2bf(v.y); h.z = f2bf(v.z); h.w = f2bf(v.w);
  *(ushort4*)(out + i) = h;
}

__global__ void cvt4_kernel(const float* __restrict__ w0, const float* __restrict__ w1,
                            const float* __restrict__ w2, const float* __restrict__ w3,
                            u16* __restrict__ o0, u16* __restrict__ o1,
                            u16* __restrict__ o2, u16* __restrict__ o3, int n) {
  const float* in = blockIdx.y == 0 ? w0 : blockIdx.y == 1 ? w1 : blockIdx.y == 2 ? w2 : w3;
  u16* out = blockIdx.y == 0 ? o0 : blockIdx.y == 1 ? o1 : blockIdx.y == 2 ? o2 : o3;
  int i = (blockIdx.x * blockDim.x + threadIdx.x) * 4;
  if (i >= n) return;
  const float4 v = *(const float4*)(in + i);
  ushort4 h;
  h.x = f2bf(v.x); h.y = f2bf(v.y); h.z = f2bf(v.z); h.w = f2bf(v.w);
  *(ushort4*)(out + i) = h;
}

// ---- 128^2 GEMM core (m97 structure) — retained for the O-projection, whose
// grid at 256^2 would be only 128 blocks (<256 CUs). ----
template <int MODE>
__device__ __forceinline__ void gemm_body(const u16* __restrict__ A,
                                          const u16* __restrict__ Bw,
                                          const float* __restrict__ bias,
                                          void* __restrict__ outp,
                                          u16* As, u16* Bs) {
  constexpr int BK = 32;
  const int tid = threadIdx.x;
  const int wave = tid >> 6;
  const int lane = tid & 63;
  const int quad = lane >> 4;
  const int l16 = lane & 15;
  const int wm = (wave >> 1) * 64;
  const int wn = (wave & 1) * 64;
  const int mBase = blockIdx.y * 128;
  const int nBase = blockIdx.x * 128;

  f32x4 acc[4][4] = {};

  const int srow = wave * 32 + (lane >> 2);
  const int soff = ((lane & 3) ^ ((lane >> 3) & 3)) * 8;
  const u16* Ag = A + (size_t)(mBase + srow) * KD + soff;
  const u16* Bg = Bw + (size_t)(nBase + srow) * KD + soff;
  u16* AsW0 = &As[(wave * 32) * BK];
  u16* AsW1 = &As[(wave * 32 + 16) * BK];
  u16* BsW0 = &Bs[(wave * 32) * BK];
  u16* BsW1 = &Bs[(wave * 32 + 16) * BK];

  const int sw = (quad ^ ((l16 >> 1) & 3)) * 8;

  for (int k0 = 0; k0 < KD; k0 += BK) {
    __syncthreads();
    async16(Ag + k0, AsW0);
    async16(Ag + 16 * KD + k0, AsW1);
    async16(Bg + k0, BsW0);
    async16(Bg + 16 * KD + k0, BsW1);
    __syncthreads();

    bf16x8 a[4], b[4];
#pragma unroll
    for (int i = 0; i < 4; i++)
      a[i] = *(const bf16x8*)&As[(wm + i * 16 + l16) * BK + sw];
#pragma unroll
    for (int j = 0; j < 4; j++)
      b[j] = *(const bf16x8*)&Bs[(wn + j * 16 + l16) * BK + sw];
#pragma unroll
    for (int i = 0; i < 4; i++)
#pragma unroll
      for (int j = 0; j < 4; j++)
        acc[i][j] = __builtin_amdgcn_mfma_f32_16x16x32_bf16(a[i], b[j], acc[i][j], 0, 0, 0);
  }

  float* outF = (float*)outp;
  u16* outH = (u16*)outp;
#pragma unroll
  for (int i = 0; i < 4; i++) {
#pragma unroll
    for (int j = 0; j < 4; j++) {
      const int col = nBase + wn + j * 16 + l16;
      const float bv = bias[col];
#pragma unroll
      for (int r = 0; r < 4; r++) {
        const int row = mBase + wm + i * 16 + quad * 4 + r;
        const float v = acc[i][j][r] + bv;
        if (MODE == 0) {
          outH[(size_t)row * ND + col] = f2bf(v);
        } else if (MODE == 1) {
          const int bb = row >> 11;
          const int t = row & (T_ - 1);
          const int h = col >> 7;
          const int d = col & (HD_ - 1);
          outH[(size_t)(((bb * H_ + h) << 7) + d) * T_ + t] = f2bf(v);
        } else {
          outF[(size_t)row * ND + col] = v;
        }
      }
    }
  }
}

__global__ __launch_bounds__(256) void gemm_out(const u16* __restrict__ A, const u16* __restrict__ Bw,
                                                const float* __restrict__ bias, float* __restrict__ outp) {
  __shared__ u16 As[128 * 32];
  __shared__ u16 Bs[128 * 32];
  gemm_body<2>(A, Bw, bias, (void*)outp, As, Bs);
}

// ---- Fused QKV GEMM: 256x256 tile, BK=64, 8 waves, 4-phase/K-tile schedule
// with counted vmcnt (never 0 in main loop), raw s_barrier (no vmcnt drain),
// setprio around MFMA clusters, XCD-swizzled blockIdx.
// Logical GEMM: C[4096][6144] = A[4096][2048] x concat(Wq,Wk,Wv)^T.
// LDS: 2 x 256x64 bf16 per operand = 128 KiB; 1 block/CU (8 waves).
// Staging of K-tile t+2 (same LDS buffer as tile t!) is issued at phases
// P2 (B halves, after last B-read at P1-close) and P3 (A halves, after last
// A-read at P2-close); single s_waitcnt vmcnt(8) per K-tile guarantees tile
// t+1 landed while tile t+2's 8 loads stay in flight across the barrier.
// Swizzle: stored 16B chunk s of row r holds global chunk s^(r&7); read side
// applies the same XOR -> conflict-free ds_read_b128 (2 rows/bank-group).
constexpr int NT8 = KD / 64;        // 32 K-tiles
constexpr int TILE8 = 256 * 64;     // LDS elems per buffer per operand

__global__ __launch_bounds__(512, 2) void gemm_qkv8(
    const u16* __restrict__ A,
    const u16* __restrict__ Wq, const u16* __restrict__ Wk, const u16* __restrict__ Wv,
    const float* __restrict__ bq, const float* __restrict__ bk, const float* __restrict__ bv,
    u16* __restrict__ Qo, u16* __restrict__ Ko, u16* __restrict__ Vo) {
  __shared__ u16 As[2 * TILE8];
  __shared__ u16 Bs[2 * TILE8];

  const int tid = threadIdx.x;
  const int wave = tid >> 6;
  const int lane = tid & 63;
  const int quad = lane >> 4;
  const int l16 = lane & 15;
  const int wm = wave >> 2;         // 0..1 (row half)
  const int wn = wave & 3;          // 0..3 (64-col strip)

  // XCD-aware block swizzle: 384 blocks, 384%8==0 -> contiguous 48-chunks/XCD
  const int orig = blockIdx.x;
  const int wg = (orig & 7) * 48 + (orig >> 3);
  const int bx = wg % 24;
  const int by = wg / 24;
  const int mBase = by * 256;
  const int nGlob = bx * 256;
  const int z = nGlob >> 11;              // 0:Q 1:K 2:V (tile never straddles)
  const int nB = nGlob & (D_ - 1);
  const u16* Bw = z == 0 ? Wq : z == 1 ? Wk : Wv;
  const float* bias = z == 0 ? bq : z == 1 ? bk : bv;

  // ---- staging geometry: per half-tile (128 rows x 64 k) each thread does 2
  // loads; wave w call c covers rows (c*8+w)*8 .. +8 (1 KiB linear LDS).
  const int lr = lane >> 3;                       // row within 8-row group
  const int lcE = ((lane & 7) ^ lr) * 8;          // pre-swizzled source chunk
  const u16* Ag = A + (size_t)mBase * KD + lcE;
  const u16* Bg = Bw + (size_t)nB * KD + lcE;
  int sRow[4], sLds[4];
#pragma unroll
  for (int h = 0; h < 2; h++)
#pragma unroll
    for (int c = 0; c < 2; c++) {
      const int rl = h * 128 + (c * 8 + wave) * 8;
      sRow[h * 2 + c] = rl + lr;                  // global row offset (per-lane)
      sLds[h * 2 + c] = rl * 64;                  // LDS elem base (wave-uniform)
    }

  // ---- fragment read offsets (chunk = (kk*4+quad) ^ (row&7), row&7 == l16&7)
  const int csw0 = (quad ^ (l16 & 7)) * 8;
  const int csw1 = ((4 + quad) ^ (l16 & 7)) * 8;

  f32x4 acc[8][4] = {};
  bf16x8 a[4][2], b0[2][2], b1[2][2];

  // ---- prologue: stage tiles 0 and 1 fully (16 loads), wait tile0 (vmcnt 8)
#pragma unroll
  for (int t = 0; t < 2; t++) {
    u16* AsD = As + t * TILE8;
    u16* BsD = Bs + t * TILE8;
#pragma unroll
    for (int k = 0; k < 4; k++) async16(Bg + (size_t)sRow[k] * KD + t * 64, BsD + sLds[k]);
#pragma unroll
    for (int k = 0; k < 4; k++) async16(Ag + (size_t)sRow[k] * KD + t * 64, AsD + sLds[k]);
  }
  asm volatile("s_waitcnt vmcnt(8)" ::: "memory");
  __builtin_amdgcn_s_barrier();
  MEMFENCE;

#pragma unroll 2
  for (int t = 0; t < NT8; ++t) {
    const int cur = t & 1;
    const u16* AsC = As + cur * TILE8;
    const u16* BsC = Bs + cur * TILE8;
    u16* AsS = (u16*)AsC;   // tile t+2 has same parity -> same buffer
    u16* BsS = (u16*)BsC;

    // ======== phase 0: read a(rows 0-63 of wave half) + b0 (cols 0-31);
    //          MFMA quadrant (qm=0, qn=0)
#pragma unroll
    for (int i = 0; i < 4; i++) {
      const int r = (wm * 128 + i * 16 + l16) * 64;
      a[i][0] = *(const bf16x8*)&AsC[r + csw0];
      a[i][1] = *(const bf16x8*)&AsC[r + csw1];
    }
#pragma unroll
    for (int j = 0; j < 2; j++) {
      const int r = (wn * 64 + j * 16 + l16) * 64;
      b0[j][0] = *(const bf16x8*)&BsC[r + csw0];
      b0[j][1] = *(const bf16x8*)&BsC[r + csw1];
    }
    MEMFENCE; __builtin_amdgcn_s_barrier(); MEMFENCE;
    __builtin_amdgcn_s_setprio(1);
#pragma unroll
    for (int i = 0; i < 4; i++)
#pragma unroll
      for (int j = 0; j < 2; j++) {
        acc[i][j] = __builtin_amdgcn_mfma_f32_16x16x32_bf16(a[i][0], b0[j][0], acc[i][j], 0, 0, 0);
        acc[i][j] = __builtin_amdgcn_mfma_f32_16x16x32_bf16(a[i][1], b0[j][1], acc[i][j], 0, 0, 0);
      }
    __builtin_amdgcn_s_setprio(0);
    MEMFENCE; __builtin_amdgcn_s_barrier(); MEMFENCE;

    // ======== phase 1: read b1 (cols 32-63); MFMA (qm=0, qn=1)
#pragma unroll
    for (int j = 0; j < 2; j++) {
      const int r = (wn * 64 + 32 + j * 16 + l16) * 64;
      b1[j][0] = *(const bf16x8*)&BsC[r + csw0];
      b1[j][1] = *(const bf16x8*)&BsC[r + csw1];
    }
    MEMFENCE; __builtin_amdgcn_s_barrier(); MEMFENCE;
    __builtin_amdgcn_s_setprio(1);
#pragma unroll
    for (int i = 0; i < 4; i++)
#pragma unroll
      for (int j = 0; j < 2; j++) {
        acc[i][2 + j] = __builtin_amdgcn_mfma_f32_16x16x32_bf16(a[i][0], b1[j][0], acc[i][2 + j], 0, 0, 0);
        acc[i][2 + j] = __builtin_amdgcn_mfma_f32_16x16x32_bf16(a[i][1], b1[j][1], acc[i][2 + j], 0, 0, 0);
      }
    __builtin_amdgcn_s_setprio(0);
    MEMFENCE; __builtin_amdgcn_s_barrier(); MEMFENCE;
    // all B reads of buf[cur] complete across the block here

    // ======== phase 2: read a(rows 64-127); issue tile t+2 B halves;
    //          MFMA (qm=1, qn=1)
#pragma unroll
    for (int i = 0; i < 4; i++) {
      const int r = (wm * 128 + 64 + i * 16 + l16) * 64;
      a[i][0] = *(const bf16x8*)&AsC[r + csw0];
      a[i][1] = *(const bf16x8*)&AsC[r + csw1];
    }
    if (t + 2 < NT8) {
#pragma unroll
      for (int k = 0; k < 4; k++)
        async16(Bg + (size_t)sRow[k] * KD + (t + 2) * 64, BsS + sLds[k]);
    }
    MEMFENCE; __builtin_amdgcn_s_barrier(); MEMFENCE;
    __builtin_amdgcn_s_setprio(1);
#pragma unroll
    for (int i = 0; i < 4; i++)
#pragma unroll
      for (int j = 0; j < 2; j++) {
        acc[4 + i][2 + j] = __builtin_amdgcn_mfma_f32_16x16x32_bf16(a[i][0], b1[j][0], acc[4 + i][2 + j], 0, 0, 0);
        acc[4 + i][2 + j] = __builtin_amdgcn_mfma_f32_16x16x32_bf16(a[i][1], b1[j][1], acc[4 + i][2 + j], 0, 0, 0);
      }
    __builtin_amdgcn_s_setprio(0);
    MEMFENCE; __builtin_amdgcn_s_barrier(); MEMFENCE;
    // all A reads of buf[cur] complete across the block here

    // ======== phase 3: issue tile t+2 A halves; MFMA (qm=1, qn=0);
    //          counted vmcnt -> tile t+1 landed, t+2's 8 loads stay in flight
    if (t + 2 < NT8) {
#pragma unroll
      for (int k = 0; k < 4; k++)
        async16(Ag + (size_t)sRow[k] * KD + (t + 2) * 64, AsS + sLds[k]);
    }
    MEMFENCE; __builtin_amdgcn_s_barrier(); MEMFENCE;
    __builtin_amdgcn_s_setprio(1);
#pragma unroll
    for (int i = 0; i < 4; i++)
#pragma unroll
      for (int j = 0; j < 2; j++) {
        acc[4 + i][j] = __builtin_amdgcn_mfma_f32_16x16x32_bf16(a[i][0], b0[j][0], acc[4 + i][j], 0, 0, 0);
        acc[4 + i][j] = __builtin_amdgcn_mfma_f32_16x16x32_bf16(a[i][1], b0[j][1], acc[4 + i][j], 0, 0, 0);
      }
    __builtin_amdgcn_s_setprio(0);
    if (t + 2 < NT8) {
      asm volatile("s_waitcnt vmcnt(8)" ::: "memory");
    } else {
      asm volatile("s_waitcnt vmcnt(0)" ::: "memory");
    }
    MEMFENCE; __builtin_amdgcn_s_barrier(); MEMFENCE;
  }

  // ---- epilogue: bias + store (bf16 row-major for Q/K; [B,H,HD,T] for V)
  u16* outH = z == 0 ? Qo : Ko;
#pragma unroll
  for (int j = 0; j < 4; j++) {
    const int col = nB + wn * 64 + j * 16 + l16;
    const float bvv = bias[col];
#pragma unroll
    for (int i = 0; i < 8; i++) {
#pragma unroll
      for (int r = 0; r < 4; r++) {
        const int row = mBase + wm * 128 + i * 16 + quad * 4 + r;
        const float v = acc[i][j][r] + bvv;
        if (z == 2) {
          const int bb = row >> 11;
          const int tt = row & (T_ - 1);
          const int hh = col >> 7;
          const int dd = col & (HD_ - 1);
          Vo[(size_t)(((bb * H_ + hh) << 7) + dd) * T_ + tt] = f2bf(v);
        } else {
          outH[(size_t)row * ND + col] = f2bf(v);
        }
      }
    }
  }
}

// ---- Flash attention: S^T formulation, paired q-tiles, ASYNC LDS double-buffer. ----
constexpr int PSTR = 72;   // P strip row stride (u16), odd 16B-group count

__global__ __launch_bounds__(256, 2) void attn_kernel(const u16* __restrict__ Q,
                                                      const u16* __restrict__ Kc,
                                                      const u16* __restrict__ Vt,
                                                      u16* __restrict__ O) {
  __shared__ u16 Ks[2][64 * 128];     // [buf][krow][d-chunk swizzled]
  __shared__ u16 Vs[2][128 * 64];     // [buf][d][krow-chunk swizzled]
  __shared__ u16 Ps[4 * 16 * PSTR];   // per-wave P strip [q][krow]
  const int tid = threadIdx.x;
  const int wave = tid >> 6;
  const int lane = tid & 63;
  const int quad = lane >> 4;
  const int l16 = lane & 15;
  const int lo = blockIdx.x;
  const int hi = 31 - lo;
  const int bh = blockIdx.y;
  const int b = bh >> 4;
  const int h = bh & 15;

  const int tIdx[2] = {lo, hi};

  // resident Q fragments (B-operand: B[k=d][n=q=l16])
  bf16x8 qf[2][4];
#pragma unroll
  for (int t = 0; t < 2; t++) {
    const u16* Qp = Q + (size_t)(b * T_ + tIdx[t] * 64 + wave * 16 + l16) * D_ + h * HD_;
#pragma unroll
    for (int kc = 0; kc < 4; kc++)
      qf[t][kc] = *(const bf16x8*)(Qp + kc * 32 + quad * 8);
  }

  f32x4 o[2][8] = {};
  float mrow[2], lrow[2];
#pragma unroll
  for (int t = 0; t < 2; t++) { mrow[t] = -__builtin_huge_valf(); lrow[t] = 0.f; }

  const u16* Kg = Kc + (size_t)(b * T_) * D_ + h * HD_;
  const u16* Vg = Vt + (size_t)((b * H_ + h) * HD_) * T_;
  u16* Pw = &Ps[wave * 16 * PSTR];
  const int swz = (l16 & 7);   // read-side row swizzle

  const u16* kgp[4];
  int klo[4];
  const u16* vgp[4];
  int vlo[4];
#pragma unroll
  for (int c = 0; c < 4; c++) {
    const int krl = wave * 16 + c * 4 + (lane >> 4);
    const int kch = (lane & 15) ^ (krl & 7);
    kgp[c] = Kg + (size_t)krl * D_ + kch * 8;
    klo[c] = (wave * 16 + c * 4) * 128;
    const int vrl = wave * 32 + c * 8 + (lane >> 3);
    const int vch = (lane & 7) ^ (vrl & 7);
    vgp[c] = Vg + (size_t)vrl * T_ + vch * 8;
    vlo[c] = (wave * 32 + c * 8) * 64;
  }

  // prologue: issue kt=0 into buf 0
#pragma unroll
  for (int c = 0; c < 4; c++) async16(kgp[c], &Ks[0][klo[c]]);
#pragma unroll
  for (int c = 0; c < 4; c++) async16(vgp[c], &Vs[0][vlo[c]]);

  for (int kt = 0; kt <= hi; kt++) {
    const int cur = kt & 1;
    __syncthreads();   // implicit vmcnt(0): buf[cur] tiles complete; all waves synced

    if (kt < hi) {     // issue next tile into buf[cur^1]; flies behind compute
      const int nxt = cur ^ 1;
#pragma unroll
      for (int c = 0; c < 4; c++) async16(kgp[c] + (size_t)(kt + 1) * 64 * D_, &Ks[nxt][klo[c]]);
#pragma unroll
      for (int c = 0; c < 4; c++) async16(vgp[c] + (size_t)(kt + 1) * 64, &Vs[nxt][vlo[c]]);
    }

#pragma unroll
    for (int t = 0; t < 2; t++) {
      if (t == 0 && kt > lo) continue;   // lo tile done (block-uniform)

      // S^T = K·Q^T: C layout -> col=l16 is q, row=quad*4+r is kcol
      f32x4 st[4];
#pragma unroll
      for (int nt = 0; nt < 4; nt++) {
        f32x4 a = {};
#pragma unroll
        for (int kc = 0; kc < 4; kc++) {
          const int pos = (kc * 4 + quad) ^ swz;
          bf16x8 kf = *(const bf16x8*)&Ks[cur][(nt * 16 + l16) * 128 + pos * 8];
          a = __builtin_amdgcn_mfma_f32_16x16x32_bf16(kf, qf[t][kc], a, 0, 0, 0);
        }
        st[nt] = a;
      }

      const bool diag = (kt == tIdx[t]);
#pragma unroll
      for (int nt = 0; nt < 4; nt++)
#pragma unroll
        for (int r = 0; r < 4; r++) {
          float v = st[nt][r] * SL2E;
          if (diag) {
            const int kcol = nt * 16 + quad * 4 + r;
            const int qrow = wave * 16 + l16;
            if (kcol > qrow) v = -__builtin_huge_valf();
          }
          st[nt][r] = v;
        }

      // online softmax: all 16 st values of this lane share q = l16
      float mx = st[0][0];
#pragma unroll
      for (int nt = 0; nt < 4; nt++)
#pragma unroll
        for (int r = 0; r < 4; r++) mx = fmaxf(mx, st[nt][r]);
      mx = fmaxf(mx, __shfl_xor(mx, 16));
      mx = fmaxf(mx, __shfl_xor(mx, 32));
      const float mnew = fmaxf(mrow[t], mx);
      const float alpha = fexp2(mrow[t] - mnew);
      mrow[t] = mnew;
      float sum = 0.f;
#pragma unroll
      for (int nt = 0; nt < 4; nt++)
#pragma unroll
        for (int r = 0; r < 4; r++) {
          const float p = fexp2(st[nt][r] - mnew);
          st[nt][r] = p;
          sum += p;
        }
      sum += __shfl_xor(sum, 16);
      sum += __shfl_xor(sum, 32);
      lrow[t] = lrow[t] * alpha + sum;

      float af[4];
#pragma unroll
      for (int r = 0; r < 4; r++) af[r] = __shfl(alpha, quad * 4 + r);
#pragma unroll
      for (int dt = 0; dt < 8; dt++)
#pragma unroll
        for (int r = 0; r < 4; r++)
          o[t][dt][r] *= af[r];

      // P store: [q=l16][k = nt*16 + quad*4 + r]
#pragma unroll
      for (int nt = 0; nt < 4; nt++) {
        ushort4 pk;
        pk.x = f2bf(st[nt][0]); pk.y = f2bf(st[nt][1]);
        pk.z = f2bf(st[nt][2]); pk.w = f2bf(st[nt][3]);
        *(ushort4*)&Pw[l16 * PSTR + nt * 16 + quad * 4] = pk;
      }
      // wave-private strip: in-wave lgkmcnt ordering suffices (no barrier)

      bf16x8 pf[2];
#pragma unroll
      for (int kc = 0; kc < 2; kc++)
        pf[kc] = *(const bf16x8*)&Pw[l16 * PSTR + kc * 32 + quad * 8];
#pragma unroll
      for (int dt = 0; dt < 8; dt++) {
#pragma unroll
        for (int kc = 0; kc < 2; kc++) {
          const int pos = (kc * 4 + quad) ^ swz;
          bf16x8 vf = *(const bf16x8*)&Vs[cur][(dt * 16 + l16) * 64 + pos * 8];
          o[t][dt] = __builtin_amdgcn_mfma_f32_16x16x32_bf16(pf[kc], vf, o[t][dt], 0, 0, 0);
        }
      }
    }
  }

#pragma unroll
  for (int t = 0; t < 2; t++) {
    float linv[4];
#pragma unroll
    for (int r = 0; r < 4; r++) linv[r] = 1.f / __shfl(lrow[t], quad * 4 + r);
#pragma unroll
    for (int dt = 0; dt < 8; dt++)
#pragma unroll
      for (int r = 0; r < 4; r++) {
        const int rowg = b * T_ + tIdx[t] * 64 + wave * 16 + quad * 4 + r;
        const int col = h * HD_ + dt * 16 + l16;
        O[(size_t)rowg * D_ + col] = f2bf(o[t][dt][r] * linv[r]);
      }
  }
}

extern "C" void kernel_launch(void* const* d_in, const int* in_sizes, int n_in,
                              void* d_out, int out_size, void* d_ws, size_t ws_size,
                              hipStream_t stream) {
  (void)in_sizes; (void)n_in; (void)out_size; (void)ws_size;
  const float* x  = (const float*)d_in[0];
  const float* wq = (const float*)d_in[2];
  const float* bq = (const float*)d_in[3];
  const float* wk = (const float*)d_in[4];
  const float* bk = (const float*)d_in[5];
  const float* wv = (const float*)d_in[6];
  const float* bv = (const float*)d_in[7];
  const float* wo = (const float*)d_in[8];
  const float* bo = (const float*)d_in[9];

  u16* ws  = (u16*)d_ws;
  u16* xb  = ws;                 // 8388608
  u16* wqb = ws + 8388608;
  u16* wkb = ws + 12582912;
  u16* wvb = ws + 16777216;
  u16* wob = ws + 20971520;
  u16* Qb  = ws + 25165824;
  u16* Kb  = ws + 33554432;
  u16* Vtb = ws + 41943040;      // [B,H,HD,T]
  u16* Ob  = ws + 50331648;

  cvt_kernel<<<8192, 256, 0, stream>>>(x, xb, 8388608);
  cvt4_kernel<<<dim3(4096, 4), 256, 0, stream>>>(wq, wk, wv, wo, wqb, wkb, wvb, wob, 4194304);

  gemm_qkv8<<<384, 512, 0, stream>>>(xb, wqb, wkb, wvb, bq, bk, bv, Qb, Kb, Vtb);
  attn_kernel<<<dim3(16, B_ * H_), 256, 0, stream>>>(Qb, Kb, Vtb, Ob);
  gemm_out<<<dim3(ND / 128, MROWS / 128), 256, 0, stream>>>(Ob, wob, bo, (float*)d_out);
}

// Round 3
// 409.738 us; speedup vs baseline: 1.0470x; 1.0470x over previous
//
#include <hip/hip_runtime.h>

typedef unsigned short u16;
typedef __bf16 bf16x8 __attribute__((ext_vector_type(8)));
typedef float f32x4 __attribute__((ext_vector_type(4)));

constexpr int B_ = 2, T_ = 2048, D_ = 2048, H_ = 16, HD_ = 128;
constexpr int MROWS = B_ * T_;   // 4096
constexpr int KD = D_;
constexpr int ND = D_;
// softmax in exp2 domain: logits pre-scaled by 1/sqrt(128) * log2(e)
#define SL2E (0.08838834764831845f * 1.4426950408889634f)

__device__ __forceinline__ u16 f2bf(float f) {
  unsigned u = __float_as_uint(f);
  u += 0x7FFF + ((u >> 16) & 1);   // RNE; inputs never NaN
  return (u16)(u >> 16);
}

__device__ __forceinline__ float fexp2(float x) { return __builtin_amdgcn_exp2f(x); }

// async global->LDS, 16B per lane; dest = wave-uniform base + lane*16
__device__ __forceinline__ void async16(const void* g, void* l) {
  __builtin_amdgcn_global_load_lds((__attribute__((address_space(1))) void*)g,
                                   (__attribute__((address_space(3))) void*)l,
                                   16, 0, 0);
}

#define MEMFENCE asm volatile("" ::: "memory")
#define BARRIER do { MEMFENCE; __builtin_amdgcn_s_barrier(); MEMFENCE; } while (0)

__global__ void cvt_kernel(const float* __restrict__ in, u16* __restrict__ out, int n) {
  int i = (blockIdx.x * blockDim.x + threadIdx.x) * 4;
  if (i >= n) return;
  const float4 v = *(const float4*)(in + i);
  ushort4 h;
  h.x = f2bf(v.x); h.y = f2bf(v.y); h.z = f2bf(v.z); h.w = f2bf(v.w);
  *(ushort4*)(out + i) = h;
}

__global__ void cvt4_kernel(const float* __restrict__ w0, const float* __restrict__ w1,
                            const float* __restrict__ w2, const float* __restrict__ w3,
                            u16* __restrict__ o0, u16* __restrict__ o1,
                            u16* __restrict__ o2, u16* __restrict__ o3, int n) {
  const float* in = blockIdx.y == 0 ? w0 : blockIdx.y == 1 ? w1 : blockIdx.y == 2 ? w2 : w3;
  u16* out = blockIdx.y == 0 ? o0 : blockIdx.y == 1 ? o1 : blockIdx.y == 2 ? o2 : o3;
  int i = (blockIdx.x * blockDim.x + threadIdx.x) * 4;
  if (i >= n) return;
  const float4 v = *(const float4*)(in + i);
  ushort4 h;
  h.x = f2bf(v.x); h.y = f2bf(v.y); h.z = f2bf(v.z); h.w = f2bf(v.w);
  *(ushort4*)(out + i) = h;
}

// ---- 128^2 GEMM core (m97 structure) — retained for the O-projection ----
template <int MODE>
__device__ __forceinline__ void gemm_body(const u16* __restrict__ A,
                                          const u16* __restrict__ Bw,
                                          const float* __restrict__ bias,
                                          void* __restrict__ outp,
                                          u16* As, u16* Bs) {
  constexpr int BK = 32;
  const int tid = threadIdx.x;
  const int wave = tid >> 6;
  const int lane = tid & 63;
  const int quad = lane >> 4;
  const int l16 = lane & 15;
  const int wm = (wave >> 1) * 64;
  const int wn = (wave & 1) * 64;
  const int mBase = blockIdx.y * 128;
  const int nBase = blockIdx.x * 128;

  f32x4 acc[4][4] = {};

  const int srow = wave * 32 + (lane >> 2);
  const int soff = ((lane & 3) ^ ((lane >> 3) & 3)) * 8;
  const u16* Ag = A + (size_t)(mBase + srow) * KD + soff;
  const u16* Bg = Bw + (size_t)(nBase + srow) * KD + soff;
  u16* AsW0 = &As[(wave * 32) * BK];
  u16* AsW1 = &As[(wave * 32 + 16) * BK];
  u16* BsW0 = &Bs[(wave * 32) * BK];
  u16* BsW1 = &Bs[(wave * 32 + 16) * BK];

  const int sw = (quad ^ ((l16 >> 1) & 3)) * 8;

  for (int k0 = 0; k0 < KD; k0 += BK) {
    __syncthreads();
    async16(Ag + k0, AsW0);
    async16(Ag + 16 * KD + k0, AsW1);
    async16(Bg + k0, BsW0);
    async16(Bg + 16 * KD + k0, BsW1);
    __syncthreads();

    bf16x8 a[4], b[4];
#pragma unroll
    for (int i = 0; i < 4; i++)
      a[i] = *(const bf16x8*)&As[(wm + i * 16 + l16) * BK + sw];
#pragma unroll
    for (int j = 0; j < 4; j++)
      b[j] = *(const bf16x8*)&Bs[(wn + j * 16 + l16) * BK + sw];
#pragma unroll
    for (int i = 0; i < 4; i++)
#pragma unroll
      for (int j = 0; j < 4; j++)
        acc[i][j] = __builtin_amdgcn_mfma_f32_16x16x32_bf16(a[i], b[j], acc[i][j], 0, 0, 0);
  }

  float* outF = (float*)outp;
  u16* outH = (u16*)outp;
#pragma unroll
  for (int i = 0; i < 4; i++) {
#pragma unroll
    for (int j = 0; j < 4; j++) {
      const int col = nBase + wn + j * 16 + l16;
      const float bv = bias[col];
#pragma unroll
      for (int r = 0; r < 4; r++) {
        const int row = mBase + wm + i * 16 + quad * 4 + r;
        const float v = acc[i][j][r] + bv;
        if (MODE == 0) {
          outH[(size_t)row * ND + col] = f2bf(v);
        } else if (MODE == 1) {
          const int bb = row >> 11;
          const int t = row & (T_ - 1);
          const int h = col >> 7;
          const int d = col & (HD_ - 1);
          outH[(size_t)(((bb * H_ + h) << 7) + d) * T_ + t] = f2bf(v);
        } else {
          outF[(size_t)row * ND + col] = v;
        }
      }
    }
  }
}

__global__ __launch_bounds__(256) void gemm_out(const u16* __restrict__ A, const u16* __restrict__ Bw,
                                                const float* __restrict__ bias, float* __restrict__ outp) {
  __shared__ u16 As[128 * 32];
  __shared__ u16 Bs[128 * 32];
  gemm_body<2>(A, Bw, bias, (void*)outp, As, Bs);
}

// ---- Fused QKV GEMM: 256x192 tile, BK=64, 8 waves, 4-phase/K-tile schedule.
// Grid = (4096/256) x (6144/192) = 16 x 32 = 512 blocks = EXACTLY 2 full
// machine rounds (no partial-round tail; R1's 384-block grid lost 25%).
// Per-wave accumulator 128x48 = 96 f32 regs (R1's 128 spilled at the 256-reg
// cap; R2's 192 + min-waves=1 couldn't even launch an 8-wave block).
// LDS = 2 x (256+192) x 64 x 2B = 112 KiB (< R1's proven 128 KiB).
// launch_bounds(512,2): 256-reg cap, 2 waves/SIMD — proven launchable (R1).
// Schedule per K-tile (R1-verified race discipline):
//   P0: read a-lo + b0,b1            | 16 MFMA (lo x b01)
//   P1: read b2                      |  8 MFMA (lo x b2)   -> B reads done
//   P2: read a-hi (reuse regs),      |  8 MFMA (hi x b2)
//       issue STAGE_B(t+2)           |                      -> A reads done
//   P3: issue STAGE_A(t+2)           | 16 MFMA (hi x b01); vmcnt(7)
// vmcnt(7): t+2's 3+4 loads may remain in flight; t+1's are guaranteed landed.
constexpr int NT8 = KD / 64;        // 32 K-tiles
constexpr int AE8 = 256 * 64;       // A elems per buffer
constexpr int BE8 = 192 * 64;       // B elems per buffer
constexpr int BUFE8 = AE8 + BE8;    // 28672 elems = 56 KiB/buffer

__global__ __launch_bounds__(512, 2) void gemm_qkv8(
    const u16* __restrict__ A, const u16* __restrict__ Wcat,
    const float* __restrict__ bq, const float* __restrict__ bk, const float* __restrict__ bv,
    u16* __restrict__ Qo, u16* __restrict__ Ko, u16* __restrict__ Vo) {
  __shared__ u16 S[2][BUFE8];

  const int tid = threadIdx.x;
  const int wave = tid >> 6;
  const int lane = tid & 63;
  const int quad = lane >> 4;
  const int l16 = lane & 15;
  const int wm = wave >> 2;         // 0..1 (128-row half)
  const int wn = wave & 3;          // 0..3 (48-col strip)

  // XCD swizzle: 512 blocks, 64/XCD; consecutive wg share bx -> B-panel
  // (192 x 2048 x 2B = 0.75 MB; 4 panels = 3 MB) hot in the XCD's 4 MiB L2.
  const int orig = blockIdx.x;
  const int wg = (orig & 7) * 64 + (orig >> 3);
  const int bx = wg >> 4;           // N tile 0..31
  const int by = wg & 15;           // M tile 0..15
  const int mBase = by * 256;
  const int nGlob = bx * 192;

  // ---- staging geometry: each call = 512 lanes x 16B = 64 rows x 128B.
  // row = c*64 + wave*8 + lr; LDS linear; source chunk pre-swizzled so
  // stored[s] = global[s ^ (row&7)] (row&7 == lr).
  const int lr = lane >> 3;
  const int lcE = ((lane & 7) ^ lr) * 8;
  const u16* Ag = A + (size_t)(mBase + wave * 8 + lr) * KD + lcE;
  const u16* Bg = Wcat + (size_t)(nGlob + wave * 8 + lr) * KD + lcE;

#define STAGE_B8(t, buf)                                                         \
  {                                                                              \
    _Pragma("unroll") for (int c = 0; c < 3; c++)                                \
        async16(Bg + (size_t)(c * 64) * KD + (size_t)(t) * 64,                   \
                &S[buf][AE8 + (c * 64 + wave * 8) * 64]);                        \
  }
#define STAGE_A8(t, buf)                                                         \
  {                                                                              \
    _Pragma("unroll") for (int c = 0; c < 4; c++)                                \
        async16(Ag + (size_t)(c * 64) * KD + (size_t)(t) * 64,                   \
                &S[buf][(c * 64 + wave * 8) * 64]);                              \
  }

  // fragment read chunk offsets: global chunk g=(k*4+quad) lives at stored
  // chunk g ^ (row&7), row&7 == l16&7 for all fragment rows.
  const int csw0 = ((0 + quad) ^ (l16 & 7)) * 8;
  const int csw1 = ((4 + quad) ^ (l16 & 7)) * 8;

  f32x4 acc[8][3] = {};
  bf16x8 a[4][2], b01[2][2], b2[2];

  // ---- prologue: stage tiles 0 and 1 (14 loads), wait tile 0 (vmcnt 7)
  STAGE_B8(0, 0);
  STAGE_A8(0, 0);
  STAGE_B8(1, 1);
  STAGE_A8(1, 1);
  asm volatile("s_waitcnt vmcnt(7)" ::: "memory");
  BARRIER;

#pragma unroll 2
  for (int t = 0; t < NT8; ++t) {
    const int cur = t & 1;
    const u16* Sc = &S[cur][0];

    // ===== P0: read a-lo (rows wm*128+0..63) + b0,b1 (cols 0..31); 16 MFMA
#pragma unroll
    for (int i = 0; i < 4; i++) {
      const int r = (wm * 128 + i * 16 + l16) * 64;
      a[i][0] = *(const bf16x8*)&Sc[r + csw0];
      a[i][1] = *(const bf16x8*)&Sc[r + csw1];
    }
#pragma unroll
    for (int j = 0; j < 2; j++) {
      const int r = AE8 + (wn * 48 + j * 16 + l16) * 64;
      b01[j][0] = *(const bf16x8*)&Sc[r + csw0];
      b01[j][1] = *(const bf16x8*)&Sc[r + csw1];
    }
    BARRIER;
    __builtin_amdgcn_s_setprio(1);
#pragma unroll
    for (int i = 0; i < 4; i++)
#pragma unroll
      for (int j = 0; j < 2; j++) {
        acc[i][j] = __builtin_amdgcn_mfma_f32_16x16x32_bf16(a[i][0], b01[j][0], acc[i][j], 0, 0, 0);
        acc[i][j] = __builtin_amdgcn_mfma_f32_16x16x32_bf16(a[i][1], b01[j][1], acc[i][j], 0, 0, 0);
      }
    __builtin_amdgcn_s_setprio(0);
    BARRIER;

    // ===== P1: read b2 (cols 32..47); 8 MFMA (lo x b2)
    {
      const int r = AE8 + (wn * 48 + 32 + l16) * 64;
      b2[0] = *(const bf16x8*)&Sc[r + csw0];
      b2[1] = *(const bf16x8*)&Sc[r + csw1];
    }
    BARRIER;
    __builtin_amdgcn_s_setprio(1);
#pragma unroll
    for (int i = 0; i < 4; i++) {
      acc[i][2] = __builtin_amdgcn_mfma_f32_16x16x32_bf16(a[i][0], b2[0], acc[i][2], 0, 0, 0);
      acc[i][2] = __builtin_amdgcn_mfma_f32_16x16x32_bf16(a[i][1], b2[1], acc[i][2], 0, 0, 0);
    }
    __builtin_amdgcn_s_setprio(0);
    BARRIER;
    // B of buf[cur] fully consumed block-wide here

    // ===== P2: read a-hi (reuse a regs); issue t+2 B stage; 8 MFMA (hi x b2)
#pragma unroll
    for (int i = 0; i < 4; i++) {
      const int r = (wm * 128 + 64 + i * 16 + l16) * 64;
      a[i][0] = *(const bf16x8*)&Sc[r + csw0];
      a[i][1] = *(const bf16x8*)&Sc[r + csw1];
    }
    if (t + 2 < NT8) STAGE_B8(t + 2, cur);
    BARRIER;
    __builtin_amdgcn_s_setprio(1);
#pragma unroll
    for (int i = 0; i < 4; i++) {
      acc[4 + i][2] = __builtin_amdgcn_mfma_f32_16x16x32_bf16(a[i][0], b2[0], acc[4 + i][2], 0, 0, 0);
      acc[4 + i][2] = __builtin_amdgcn_mfma_f32_16x16x32_bf16(a[i][1], b2[1], acc[4 + i][2], 0, 0, 0);
    }
    __builtin_amdgcn_s_setprio(0);
    BARRIER;
    // A of buf[cur] fully consumed block-wide here

    // ===== P3: issue t+2 A stage; 16 MFMA (hi x b01); counted vmcnt; barrier
    if (t + 2 < NT8) STAGE_A8(t + 2, cur);
    BARRIER;
    __builtin_amdgcn_s_setprio(1);
#pragma unroll
    for (int i = 0; i < 4; i++)
#pragma unroll
      for (int j = 0; j < 2; j++) {
        acc[4 + i][j] = __builtin_amdgcn_mfma_f32_16x16x32_bf16(a[i][0], b01[j][0], acc[4 + i][j], 0, 0, 0);
        acc[4 + i][j] = __builtin_amdgcn_mfma_f32_16x16x32_bf16(a[i][1], b01[j][1], acc[4 + i][j], 0, 0, 0);
      }
    __builtin_amdgcn_s_setprio(0);
    if (t + 2 < NT8) {
      asm volatile("s_waitcnt vmcnt(7)" ::: "memory");   // t+1 landed; t+2 in flight
    } else {
      asm volatile("s_waitcnt vmcnt(0)" ::: "memory");
    }
    BARRIER;
  }

  // ---- epilogue: bias + store; per-column Q/K/V select (N concat axis).
  // 16-col fragments never straddle a 2048 boundary (16 | 2048).
#pragma unroll
  for (int jj = 0; jj < 3; jj++) {
    const int col = nGlob + wn * 48 + jj * 16 + l16;
    const int z = col >> 11;          // 0:Q 1:K 2:V
    const int c2 = col & (D_ - 1);
    const float bvv = (z == 0 ? bq : z == 1 ? bk : bv)[c2];
    u16* outH = z == 0 ? Qo : Ko;
#pragma unroll
    for (int ih = 0; ih < 2; ih++) {
#pragma unroll
      for (int i = 0; i < 4; i++) {
#pragma unroll
        for (int r = 0; r < 4; r++) {
          const int row = mBase + wm * 128 + ih * 64 + i * 16 + quad * 4 + r;
          const float v = acc[ih * 4 + i][jj][r] + bvv;
          if (z == 2) {
            const int bb = row >> 11;
            const int tt = row & (T_ - 1);
            const int hh = c2 >> 7;
            const int dd = c2 & (HD_ - 1);
            Vo[(size_t)(((bb * H_ + hh) << 7) + dd) * T_ + tt] = f2bf(v);
          } else {
            outH[(size_t)row * ND + c2] = f2bf(v);
          }
        }
      }
    }
  }
#undef STAGE_A8
#undef STAGE_B8
}

// ---- Flash attention: S^T formulation, paired q-tiles, ASYNC LDS double-buffer. ----
constexpr int PSTR = 72;   // P strip row stride (u16), odd 16B-group count

__global__ __launch_bounds__(256, 2) void attn_kernel(const u16* __restrict__ Q,
                                                      const u16* __restrict__ Kc,
                                                      const u16* __restrict__ Vt,
                                                      u16* __restrict__ O) {
  __shared__ u16 Ks[2][64 * 128];     // [buf][krow][d-chunk swizzled]
  __shared__ u16 Vs[2][128 * 64];     // [buf][d][krow-chunk swizzled]
  __shared__ u16 Ps[4 * 16 * PSTR];   // per-wave P strip [q][krow]
  const int tid = threadIdx.x;
  const int wave = tid >> 6;
  const int lane = tid & 63;
  const int quad = lane >> 4;
  const int l16 = lane & 15;
  const int lo = blockIdx.x;
  const int hi = 31 - lo;
  const int bh = blockIdx.y;
  const int b = bh >> 4;
  const int h = bh & 15;

  const int tIdx[2] = {lo, hi};

  // resident Q fragments (B-operand: B[k=d][n=q=l16])
  bf16x8 qf[2][4];
#pragma unroll
  for (int t = 0; t < 2; t++) {
    const u16* Qp = Q + (size_t)(b * T_ + tIdx[t] * 64 + wave * 16 + l16) * D_ + h * HD_;
#pragma unroll
    for (int kc = 0; kc < 4; kc++)
      qf[t][kc] = *(const bf16x8*)(Qp + kc * 32 + quad * 8);
  }

  f32x4 o[2][8] = {};
  float mrow[2], lrow[2];
#pragma unroll
  for (int t = 0; t < 2; t++) { mrow[t] = -__builtin_huge_valf(); lrow[t] = 0.f; }

  const u16* Kg = Kc + (size_t)(b * T_) * D_ + h * HD_;
  const u16* Vg = Vt + (size_t)((b * H_ + h) * HD_) * T_;
  u16* Pw = &Ps[wave * 16 * PSTR];
  const int swz = (l16 & 7);   // read-side row swizzle

  const u16* kgp[4];
  int klo[4];
  const u16* vgp[4];
  int vlo[4];
#pragma unroll
  for (int c = 0; c < 4; c++) {
    const int krl = wave * 16 + c * 4 + (lane >> 4);
    const int kch = (lane & 15) ^ (krl & 7);
    kgp[c] = Kg + (size_t)krl * D_ + kch * 8;
    klo[c] = (wave * 16 + c * 4) * 128;
    const int vrl = wave * 32 + c * 8 + (lane >> 3);
    const int vch = (lane & 7) ^ (vrl & 7);
    vgp[c] = Vg + (size_t)vrl * T_ + vch * 8;
    vlo[c] = (wave * 32 + c * 8) * 64;
  }

  // prologue: issue kt=0 into buf 0
#pragma unroll
  for (int c = 0; c < 4; c++) async16(kgp[c], &Ks[0][klo[c]]);
#pragma unroll
  for (int c = 0; c < 4; c++) async16(vgp[c], &Vs[0][vlo[c]]);

  for (int kt = 0; kt <= hi; kt++) {
    const int cur = kt & 1;
    __syncthreads();   // implicit vmcnt(0): buf[cur] tiles complete; all waves synced

    if (kt < hi) {     // issue next tile into buf[cur^1]; flies behind compute
      const int nxt = cur ^ 1;
#pragma unroll
      for (int c = 0; c < 4; c++) async16(kgp[c] + (size_t)(kt + 1) * 64 * D_, &Ks[nxt][klo[c]]);
#pragma unroll
      for (int c = 0; c < 4; c++) async16(vgp[c] + (size_t)(kt + 1) * 64, &Vs[nxt][vlo[c]]);
    }

#pragma unroll
    for (int t = 0; t < 2; t++) {
      if (t == 0 && kt > lo) continue;   // lo tile done (block-uniform)

      // S^T = K·Q^T: C layout -> col=l16 is q, row=quad*4+r is kcol
      f32x4 st[4];
#pragma unroll
      for (int nt = 0; nt < 4; nt++) {
        f32x4 a = {};
#pragma unroll
        for (int kc = 0; kc < 4; kc++) {
          const int pos = (kc * 4 + quad) ^ swz;
          bf16x8 kf = *(const bf16x8*)&Ks[cur][(nt * 16 + l16) * 128 + pos * 8];
          a = __builtin_amdgcn_mfma_f32_16x16x32_bf16(kf, qf[t][kc], a, 0, 0, 0);
        }
        st[nt] = a;
      }

      const bool diag = (kt == tIdx[t]);
#pragma unroll
      for (int nt = 0; nt < 4; nt++)
#pragma unroll
        for (int r = 0; r < 4; r++) {
          float v = st[nt][r] * SL2E;
          if (diag) {
            const int kcol = nt * 16 + quad * 4 + r;
            const int qrow = wave * 16 + l16;
            if (kcol > qrow) v = -__builtin_huge_valf();
          }
          st[nt][r] = v;
        }

      // online softmax: all 16 st values of this lane share q = l16
      float mx = st[0][0];
#pragma unroll
      for (int nt = 0; nt < 4; nt++)
#pragma unroll
        for (int r = 0; r < 4; r++) mx = fmaxf(mx, st[nt][r]);
      mx = fmaxf(mx, __shfl_xor(mx, 16));
      mx = fmaxf(mx, __shfl_xor(mx, 32));
      const float mnew = fmaxf(mrow[t], mx);
      const float alpha = fexp2(mrow[t] - mnew);
      mrow[t] = mnew;
      float sum = 0.f;
#pragma unroll
      for (int nt = 0; nt < 4; nt++)
#pragma unroll
        for (int r = 0; r < 4; r++) {
          const float p = fexp2(st[nt][r] - mnew);
          st[nt][r] = p;
          sum += p;
        }
      sum += __shfl_xor(sum, 16);
      sum += __shfl_xor(sum, 32);
      lrow[t] = lrow[t] * alpha + sum;

      float af[4];
#pragma unroll
      for (int r = 0; r < 4; r++) af[r] = __shfl(alpha, quad * 4 + r);
#pragma unroll
      for (int dt = 0; dt < 8; dt++)
#pragma unroll
        for (int r = 0; r < 4; r++)
          o[t][dt][r] *= af[r];

      // P store: [q=l16][k = nt*16 + quad*4 + r]
#pragma unroll
      for (int nt = 0; nt < 4; nt++) {
        ushort4 pk;
        pk.x = f2bf(st[nt][0]); pk.y = f2bf(st[nt][1]);
        pk.z = f2bf(st[nt][2]); pk.w = f2bf(st[nt][3]);
        *(ushort4*)&Pw[l16 * PSTR + nt * 16 + quad * 4] = pk;
      }
      // wave-private strip: in-wave lgkmcnt ordering suffices (no barrier)

      bf16x8 pf[2];
#pragma unroll
      for (int kc = 0; kc < 2; kc++)
        pf[kc] = *(const bf16x8*)&Pw[l16 * PSTR + kc * 32 + quad * 8];
#pragma unroll
      for (int dt = 0; dt < 8; dt++) {
#pragma unroll
        for (int kc = 0; kc < 2; kc++) {
          const int pos = (kc * 4 + quad) ^ swz;
          bf16x8 vf = *(const bf16x8*)&Vs[cur][(dt * 16 + l16) * 64 + pos * 8];
          o[t][dt] = __builtin_amdgcn_mfma_f32_16x16x32_bf16(pf[kc], vf, o[t][dt], 0, 0, 0);
        }
      }
    }
  }

#pragma unroll
  for (int t = 0; t < 2; t++) {
    float linv[4];
#pragma unroll
    for (int r = 0; r < 4; r++) linv[r] = 1.f / __shfl(lrow[t], quad * 4 + r);
#pragma unroll
    for (int dt = 0; dt < 8; dt++)
#pragma unroll
      for (int r = 0; r < 4; r++) {
        const int rowg = b * T_ + tIdx[t] * 64 + wave * 16 + quad * 4 + r;
        const int col = h * HD_ + dt * 16 + l16;
        O[(size_t)rowg * D_ + col] = f2bf(o[t][dt][r] * linv[r]);
      }
  }
}

extern "C" void kernel_launch(void* const* d_in, const int* in_sizes, int n_in,
                              void* d_out, int out_size, void* d_ws, size_t ws_size,
                              hipStream_t stream) {
  (void)in_sizes; (void)n_in; (void)out_size; (void)ws_size;
  const float* x  = (const float*)d_in[0];
  const float* wq = (const float*)d_in[2];
  const float* bq = (const float*)d_in[3];
  const float* wk = (const float*)d_in[4];
  const float* bk = (const float*)d_in[5];
  const float* wv = (const float*)d_in[6];
  const float* bv = (const float*)d_in[7];
  const float* wo = (const float*)d_in[8];
  const float* bo = (const float*)d_in[9];

  u16* ws  = (u16*)d_ws;
  u16* xb  = ws;                 // 8388608
  u16* wqb = ws + 8388608;       // wq|wk|wv contiguous -> concat weight base
  u16* wkb = ws + 12582912;
  u16* wvb = ws + 16777216;
  u16* wob = ws + 20971520;
  u16* Qb  = ws + 25165824;
  u16* Kb  = ws + 33554432;
  u16* Vtb = ws + 41943040;      // [B,H,HD,T]
  u16* Ob  = ws + 50331648;

  cvt_kernel<<<8192, 256, 0, stream>>>(x, xb, 8388608);
  cvt4_kernel<<<dim3(4096, 4), 256, 0, stream>>>(wq, wk, wv, wo, wqb, wkb, wvb, wob, 4194304);

  gemm_qkv8<<<512, 512, 0, stream>>>(xb, wqb, bq, bk, bv, Qb, Kb, Vtb);
  attn_kernel<<<dim3(16, B_ * H_), 256, 0, stream>>>(Qb, Kb, Vtb, Ob);
  gemm_out<<<dim3(ND / 128, MROWS / 128), 256, 0, stream>>>(Ob, wob, bo, (float*)d_out);
}

// Round 4
// 391.092 us; speedup vs baseline: 1.0969x; 1.0477x over previous
//
#include <hip/hip_runtime.h>

typedef unsigned short u16;
typedef __bf16 bf16x8 __attribute__((ext_vector_type(8)));
typedef float f32x4 __attribute__((ext_vector_type(4)));

constexpr int B_ = 2, T_ = 2048, D_ = 2048, H_ = 16, HD_ = 128;
constexpr int MROWS = B_ * T_;   // 4096
constexpr int KD = D_;
constexpr int ND = D_;
// softmax in exp2 domain: logits pre-scaled by 1/sqrt(128) * log2(e)
#define SL2E (0.08838834764831845f * 1.4426950408889634f)

__device__ __forceinline__ u16 f2bf(float f) {
  unsigned u = __float_as_uint(f);
  u += 0x7FFF + ((u >> 16) & 1);   // RNE; inputs never NaN
  return (u16)(u >> 16);
}

__device__ __forceinline__ float fexp2(float x) { return __builtin_amdgcn_exp2f(x); }

// async global->LDS, 16B per lane; dest = wave-uniform base + lane*16
__device__ __forceinline__ void async16(const void* g, void* l) {
  __builtin_amdgcn_global_load_lds((__attribute__((address_space(1))) void*)g,
                                   (__attribute__((address_space(3))) void*)l,
                                   16, 0, 0);
}

// single fused f32->bf16 conversion kernel: 6 slabs of 4194304 elems each
// (x lo, x hi, wq, wk, wv, wo) -> one launch instead of two.
__global__ void cvt6_kernel(const float* __restrict__ x,
                            const float* __restrict__ w0, const float* __restrict__ w1,
                            const float* __restrict__ w2, const float* __restrict__ w3,
                            u16* __restrict__ xo,
                            u16* __restrict__ o0, u16* __restrict__ o1,
                            u16* __restrict__ o2, u16* __restrict__ o3) {
  const int y = blockIdx.y;
  const float* in = y == 0 ? x : y == 1 ? x + 4194304 :
                    y == 2 ? w0 : y == 3 ? w1 : y == 4 ? w2 : w3;
  u16* out = y == 0 ? xo : y == 1 ? xo + 4194304 :
             y == 2 ? o0 : y == 3 ? o1 : y == 4 ? o2 : o3;
  const int i = (blockIdx.x * blockDim.x + threadIdx.x) * 4;
  const float4 v = *(const float4*)(in + i);
  ushort4 h;
  h.x = f2bf(v.x); h.y = f2bf(v.y); h.z = f2bf(v.z); h.w = f2bf(v.w);
  *(ushort4*)(out + i) = h;
}

// ---- GEMM core (R0-proven: conflicts == 0, ~806 TF machine rate) ----
template <int MODE>
__device__ __forceinline__ void gemm_body(const u16* __restrict__ A,
                                          const u16* __restrict__ Bw,
                                          const float* __restrict__ bias,
                                          void* __restrict__ outp,
                                          u16* As, u16* Bs) {
  constexpr int BK = 32;
  const int tid = threadIdx.x;
  const int wave = tid >> 6;
  const int lane = tid & 63;
  const int quad = lane >> 4;
  const int l16 = lane & 15;
  const int wm = (wave >> 1) * 64;
  const int wn = (wave & 1) * 64;
  const int mBase = blockIdx.y * 128;
  const int nBase = blockIdx.x * 128;

  f32x4 acc[4][4] = {};

  const int srow = wave * 32 + (lane >> 2);
  const int soff = ((lane & 3) ^ ((lane >> 3) & 3)) * 8;
  const u16* Ag = A + (size_t)(mBase + srow) * KD + soff;
  const u16* Bg = Bw + (size_t)(nBase + srow) * KD + soff;
  u16* AsW0 = &As[(wave * 32) * BK];
  u16* AsW1 = &As[(wave * 32 + 16) * BK];
  u16* BsW0 = &Bs[(wave * 32) * BK];
  u16* BsW1 = &Bs[(wave * 32 + 16) * BK];

  const int sw = (quad ^ ((l16 >> 1) & 3)) * 8;

  for (int k0 = 0; k0 < KD; k0 += BK) {
    __syncthreads();
    async16(Ag + k0, AsW0);
    async16(Ag + 16 * KD + k0, AsW1);
    async16(Bg + k0, BsW0);
    async16(Bg + 16 * KD + k0, BsW1);
    __syncthreads();

    bf16x8 a[4], b[4];
#pragma unroll
    for (int i = 0; i < 4; i++)
      a[i] = *(const bf16x8*)&As[(wm + i * 16 + l16) * BK + sw];
#pragma unroll
    for (int j = 0; j < 4; j++)
      b[j] = *(const bf16x8*)&Bs[(wn + j * 16 + l16) * BK + sw];
#pragma unroll
    for (int i = 0; i < 4; i++)
#pragma unroll
      for (int j = 0; j < 4; j++)
        acc[i][j] = __builtin_amdgcn_mfma_f32_16x16x32_bf16(a[i], b[j], acc[i][j], 0, 0, 0);
  }

  float* outF = (float*)outp;
  u16* outH = (u16*)outp;
#pragma unroll
  for (int i = 0; i < 4; i++) {
#pragma unroll
    for (int j = 0; j < 4; j++) {
      const int col = nBase + wn + j * 16 + l16;
      const float bv = bias[col];
#pragma unroll
      for (int r = 0; r < 4; r++) {
        const int row = mBase + wm + i * 16 + quad * 4 + r;
        const float v = acc[i][j][r] + bv;
        if (MODE == 0) {
          outH[(size_t)row * ND + col] = f2bf(v);
        } else if (MODE == 1) {
          const int bb = row >> 11;
          const int t = row & (T_ - 1);
          const int h = col >> 7;
          const int d = col & (HD_ - 1);
          outH[(size_t)(((bb * H_ + h) << 7) + d) * T_ + t] = f2bf(v);
        } else {
          outF[(size_t)row * ND + col] = v;
        }
      }
    }
  }
}

__global__ __launch_bounds__(256) void gemm_qkv(const u16* __restrict__ A,
                                                const u16* __restrict__ Wq, const u16* __restrict__ Wk,
                                                const u16* __restrict__ Wv,
                                                const float* __restrict__ bq, const float* __restrict__ bk,
                                                const float* __restrict__ bv,
                                                u16* __restrict__ Qo, u16* __restrict__ Ko,
                                                u16* __restrict__ Vo) {
  __shared__ u16 As[128 * 32];
  __shared__ u16 Bs[128 * 32];
  const int z = blockIdx.z;
  const u16* Bw = z == 0 ? Wq : z == 1 ? Wk : Wv;
  const float* bias = z == 0 ? bq : z == 1 ? bk : bv;
  if (z == 2)
    gemm_body<1>(A, Bw, bias, (void*)Vo, As, Bs);
  else
    gemm_body<0>(A, Bw, bias, (void*)(z == 0 ? Qo : Ko), As, Bs);
}

__global__ __launch_bounds__(256) void gemm_out(const u16* __restrict__ A, const u16* __restrict__ Bw,
                                                const float* __restrict__ bias, float* __restrict__ outp) {
  __shared__ u16 As[128 * 32];
  __shared__ u16 Bs[128 * 32];
  gemm_body<2>(A, Bw, bias, (void*)outp, As, Bs);
}

// ---- Flash attention: S^T formulation, paired q-tiles, ASYNC LDS double-buffer.
// R4 additions (T13 + deferred sum reduce):
//  * defer-max: when the tile max grows by <= 8 (exp2 domain) across the whole
//    wave, keep the old running max -> skip alpha exp2, the 4-shfl alpha
//    broadcast, and the 32-reg O rescale. P is then bounded by 2^8, safe in
//    bf16/f32 (HK THR=8; m239 refcheck'd).
//  * lrow kept as PER-LANE partial sums; the cross-quad shfl reduce moves from
//    per-tile-step (2 shfl) to once in the epilogue (alpha is row-uniform, so
//    partials scale identically).
constexpr int PSTR = 72;   // P strip row stride (u16), odd 16B-group count

__global__ __launch_bounds__(256, 2) void attn_kernel(const u16* __restrict__ Q,
                                                      const u16* __restrict__ Kc,
                                                      const u16* __restrict__ Vt,
                                                      u16* __restrict__ O) {
  __shared__ u16 Ks[2][64 * 128];     // [buf][krow][d-chunk swizzled]
  __shared__ u16 Vs[2][128 * 64];     // [buf][d][krow-chunk swizzled]
  __shared__ u16 Ps[4 * 16 * PSTR];   // per-wave P strip [q][krow]
  const int tid = threadIdx.x;
  const int wave = tid >> 6;
  const int lane = tid & 63;
  const int quad = lane >> 4;
  const int l16 = lane & 15;
  const int lo = blockIdx.x;
  const int hi = 31 - lo;
  const int bh = blockIdx.y;
  const int b = bh >> 4;
  const int h = bh & 15;

  const int tIdx[2] = {lo, hi};

  // resident Q fragments (B-operand: B[k=d][n=q=l16])
  bf16x8 qf[2][4];
#pragma unroll
  for (int t = 0; t < 2; t++) {
    const u16* Qp = Q + (size_t)(b * T_ + tIdx[t] * 64 + wave * 16 + l16) * D_ + h * HD_;
#pragma unroll
    for (int kc = 0; kc < 4; kc++)
      qf[t][kc] = *(const bf16x8*)(Qp + kc * 32 + quad * 8);
  }

  f32x4 o[2][8] = {};
  float mrow[2], lrow[2];
#pragma unroll
  for (int t = 0; t < 2; t++) { mrow[t] = -__builtin_huge_valf(); lrow[t] = 0.f; }

  const u16* Kg = Kc + (size_t)(b * T_) * D_ + h * HD_;
  const u16* Vg = Vt + (size_t)((b * H_ + h) * HD_) * T_;
  u16* Pw = &Ps[wave * 16 * PSTR];
  const int swz = (l16 & 7);   // read-side row swizzle

  const u16* kgp[4];
  int klo[4];
  const u16* vgp[4];
  int vlo[4];
#pragma unroll
  for (int c = 0; c < 4; c++) {
    const int krl = wave * 16 + c * 4 + (lane >> 4);
    const int kch = (lane & 15) ^ (krl & 7);
    kgp[c] = Kg + (size_t)krl * D_ + kch * 8;
    klo[c] = (wave * 16 + c * 4) * 128;
    const int vrl = wave * 32 + c * 8 + (lane >> 3);
    const int vch = (lane & 7) ^ (vrl & 7);
    vgp[c] = Vg + (size_t)vrl * T_ + vch * 8;
    vlo[c] = (wave * 32 + c * 8) * 64;
  }

  // prologue: issue kt=0 into buf 0
#pragma unroll
  for (int c = 0; c < 4; c++) async16(kgp[c], &Ks[0][klo[c]]);
#pragma unroll
  for (int c = 0; c < 4; c++) async16(vgp[c], &Vs[0][vlo[c]]);

  for (int kt = 0; kt <= hi; kt++) {
    const int cur = kt & 1;
    __syncthreads();   // implicit vmcnt(0): buf[cur] tiles complete; all waves synced

    if (kt < hi) {     // issue next tile into buf[cur^1]; flies behind compute
      const int nxt = cur ^ 1;
#pragma unroll
      for (int c = 0; c < 4; c++) async16(kgp[c] + (size_t)(kt + 1) * 64 * D_, &Ks[nxt][klo[c]]);
#pragma unroll
      for (int c = 0; c < 4; c++) async16(vgp[c] + (size_t)(kt + 1) * 64, &Vs[nxt][vlo[c]]);
    }

#pragma unroll
    for (int t = 0; t < 2; t++) {
      if (t == 0 && kt > lo) continue;   // lo tile done (block-uniform)

      // S^T = K·Q^T: C layout -> col=l16 is q, row=quad*4+r is kcol
      f32x4 st[4];
#pragma unroll
      for (int nt = 0; nt < 4; nt++) {
        f32x4 a = {};
#pragma unroll
        for (int kc = 0; kc < 4; kc++) {
          const int pos = (kc * 4 + quad) ^ swz;
          bf16x8 kf = *(const bf16x8*)&Ks[cur][(nt * 16 + l16) * 128 + pos * 8];
          a = __builtin_amdgcn_mfma_f32_16x16x32_bf16(kf, qf[t][kc], a, 0, 0, 0);
        }
        st[nt] = a;
      }

      const bool diag = (kt == tIdx[t]);
#pragma unroll
      for (int nt = 0; nt < 4; nt++)
#pragma unroll
        for (int r = 0; r < 4; r++) {
          float v = st[nt][r] * SL2E;
          if (diag) {
            const int kcol = nt * 16 + quad * 4 + r;
            const int qrow = wave * 16 + l16;
            if (kcol > qrow) v = -__builtin_huge_valf();
          }
          st[nt][r] = v;
        }

      // online softmax: all 16 st values of this lane share q = l16
      float mx = st[0][0];
#pragma unroll
      for (int nt = 0; nt < 4; nt++)
#pragma unroll
        for (int r = 0; r < 4; r++) mx = fmaxf(mx, st[nt][r]);
      mx = fmaxf(mx, __shfl_xor(mx, 16));
      mx = fmaxf(mx, __shfl_xor(mx, 32));

      if (__all(mx - mrow[t] <= 8.0f)) {
        // T13 defer-max: keep old max; P bounded by 2^8; no O-rescale.
        const float mold = mrow[t];
        float sum = 0.f;
#pragma unroll
        for (int nt = 0; nt < 4; nt++)
#pragma unroll
          for (int r = 0; r < 4; r++) {
            const float p = fexp2(st[nt][r] - mold);
            st[nt][r] = p;
            sum += p;
          }
        lrow[t] += sum;          // per-lane partial; reduced in epilogue
      } else {
        const float mnew = fmaxf(mrow[t], mx);
        const float alpha = fexp2(mrow[t] - mnew);
        mrow[t] = mnew;
        float sum = 0.f;
#pragma unroll
        for (int nt = 0; nt < 4; nt++)
#pragma unroll
          for (int r = 0; r < 4; r++) {
            const float p = fexp2(st[nt][r] - mnew);
            st[nt][r] = p;
            sum += p;
          }
        lrow[t] = lrow[t] * alpha + sum;

        float af[4];
#pragma unroll
        for (int r = 0; r < 4; r++) af[r] = __shfl(alpha, quad * 4 + r);
#pragma unroll
        for (int dt = 0; dt < 8; dt++)
#pragma unroll
          for (int r = 0; r < 4; r++)
            o[t][dt][r] *= af[r];
      }

      // P store: [q=l16][k = nt*16 + quad*4 + r]
#pragma unroll
      for (int nt = 0; nt < 4; nt++) {
        ushort4 pk;
        pk.x = f2bf(st[nt][0]); pk.y = f2bf(st[nt][1]);
        pk.z = f2bf(st[nt][2]); pk.w = f2bf(st[nt][3]);
        *(ushort4*)&Pw[l16 * PSTR + nt * 16 + quad * 4] = pk;
      }
      // wave-private strip: in-wave lgkmcnt ordering suffices (no barrier)

      bf16x8 pf[2];
#pragma unroll
      for (int kc = 0; kc < 2; kc++)
        pf[kc] = *(const bf16x8*)&Pw[l16 * PSTR + kc * 32 + quad * 8];
#pragma unroll
      for (int dt = 0; dt < 8; dt++) {
#pragma unroll
        for (int kc = 0; kc < 2; kc++) {
          const int pos = (kc * 4 + quad) ^ swz;
          bf16x8 vf = *(const bf16x8*)&Vs[cur][(dt * 16 + l16) * 64 + pos * 8];
          o[t][dt] = __builtin_amdgcn_mfma_f32_16x16x32_bf16(pf[kc], vf, o[t][dt], 0, 0, 0);
        }
      }
    }
  }

#pragma unroll
  for (int t = 0; t < 2; t++) {
    // deferred cross-quad reduce of the per-lane partial sums
    float ltot = lrow[t];
    ltot += __shfl_xor(ltot, 16);
    ltot += __shfl_xor(ltot, 32);
    float linv[4];
#pragma unroll
    for (int r = 0; r < 4; r++) linv[r] = 1.f / __shfl(ltot, quad * 4 + r);
#pragma unroll
    for (int dt = 0; dt < 8; dt++)
#pragma unroll
      for (int r = 0; r < 4; r++) {
        const int rowg = b * T_ + tIdx[t] * 64 + wave * 16 + quad * 4 + r;
        const int col = h * HD_ + dt * 16 + l16;
        O[(size_t)rowg * D_ + col] = f2bf(o[t][dt][r] * linv[r]);
      }
  }
}

extern "C" void kernel_launch(void* const* d_in, const int* in_sizes, int n_in,
                              void* d_out, int out_size, void* d_ws, size_t ws_size,
                              hipStream_t stream) {
  (void)in_sizes; (void)n_in; (void)out_size; (void)ws_size;
  const float* x  = (const float*)d_in[0];
  const float* wq = (const float*)d_in[2];
  const float* bq = (const float*)d_in[3];
  const float* wk = (const float*)d_in[4];
  const float* bk = (const float*)d_in[5];
  const float* wv = (const float*)d_in[6];
  const float* bv = (const float*)d_in[7];
  const float* wo = (const float*)d_in[8];
  const float* bo = (const float*)d_in[9];

  u16* ws  = (u16*)d_ws;
  u16* xb  = ws;                 // 8388608
  u16* wqb = ws + 8388608;
  u16* wkb = ws + 12582912;
  u16* wvb = ws + 16777216;
  u16* wob = ws + 20971520;
  u16* Qb  = ws + 25165824;
  u16* Kb  = ws + 33554432;
  u16* Vtb = ws + 41943040;      // [B,H,HD,T]
  u16* Ob  = ws + 50331648;

  cvt6_kernel<<<dim3(4096, 6), 256, 0, stream>>>(x, wq, wk, wv, wo,
                                                 xb, wqb, wkb, wvb, wob);

  dim3 gg(ND / 128, MROWS / 128, 3);
  gemm_qkv<<<gg, 256, 0, stream>>>(xb, wqb, wkb, wvb, bq, bk, bv, Qb, Kb, Vtb);
  attn_kernel<<<dim3(16, B_ * H_), 256, 0, stream>>>(Qb, Kb, Vtb, Ob);
  gemm_out<<<dim3(ND / 128, MROWS / 128), 256, 0, stream>>>(Ob, wob, bo, (float*)d_out);
}